// Round 12
// baseline (249.061 us; speedup 1.0000x reference)
//
#include <hip/hip_runtime.h>
#include <hip/hip_bf16.h>
#include <math.h>
#include <type_traits>

typedef __bf16 bf16_t;
typedef __bf16 bf16x8 __attribute__((ext_vector_type(8)));
typedef float f32x4 __attribute__((ext_vector_type(4)));

__device__ __forceinline__ void gload_lds16(const void* g, void* l) {
  __builtin_amdgcn_global_load_lds((const __attribute__((address_space(1))) void*)g,
                                   (__attribute__((address_space(3))) void*)l, 16, 0, 0);
}

template <int N> __device__ __forceinline__ void wait_vm() {
  static_assert(N >= 0 && N <= 12, "unsupported vmcnt");
  if constexpr (N == 0)  asm volatile("s_waitcnt vmcnt(0)" ::: "memory");
  else if constexpr (N == 1)  asm volatile("s_waitcnt vmcnt(1)" ::: "memory");
  else if constexpr (N == 2)  asm volatile("s_waitcnt vmcnt(2)" ::: "memory");
  else if constexpr (N == 3)  asm volatile("s_waitcnt vmcnt(3)" ::: "memory");
  else if constexpr (N == 4)  asm volatile("s_waitcnt vmcnt(4)" ::: "memory");
  else if constexpr (N == 5)  asm volatile("s_waitcnt vmcnt(5)" ::: "memory");
  else if constexpr (N == 6)  asm volatile("s_waitcnt vmcnt(6)" ::: "memory");
  else if constexpr (N == 7)  asm volatile("s_waitcnt vmcnt(7)" ::: "memory");
  else if constexpr (N == 8)  asm volatile("s_waitcnt vmcnt(8)" ::: "memory");
  else if constexpr (N == 12) asm volatile("s_waitcnt vmcnt(12)" ::: "memory");
}

// ------------- transpose + cast: in fp32 [K][N] -> out bf16 [N][K] -------------
__global__ void transk(const float* __restrict__ in, bf16_t* __restrict__ out,
                       int K, int N) {
  __shared__ float t[32][33];
  int n0 = blockIdx.x * 32, k0 = blockIdx.y * 32;
  int tx = threadIdx.x & 31, ty = threadIdx.x >> 5;  // ty 0..7
#pragma unroll
  for (int r = ty; r < 32; r += 8) t[r][tx] = in[(size_t)(k0 + r) * N + n0 + tx];
  __syncthreads();
#pragma unroll
  for (int r = ty; r < 32; r += 8)
    out[(size_t)(n0 + r) * K + k0 + tx] = (bf16_t)t[tx][r];
}

// ------------- row offsets: ro[n] = lower_bound(dst, n) (dst sorted) -------------
__global__ void rowoffk(const int* __restrict__ dst, int* __restrict__ ro, int N, int E) {
  int n = blockIdx.x * blockDim.x + threadIdx.x;
  if (n > N) return;
  if (n == N) { ro[N] = E; return; }
  int lo = 0, hi = E;
  while (lo < hi) { int mid = (lo + hi) >> 1; if (dst[mid] < n) lo = mid + 1; else hi = mid; }
  ro[n] = lo;
}

// ------------- el/er: per node, per head dot(h, al), dot(h, ar) -------------
__global__ void elerk(const bf16_t* __restrict__ Hb, const float* __restrict__ al,
                      const float* __restrict__ ar, float* __restrict__ el,
                      float* __restrict__ er, int N) {
  int node = blockIdx.x * 4 + (threadIdx.x >> 6);
  int lane = threadIdx.x & 63;
  if (node >= N) return;
  bf16x8 v = *(const bf16x8*)(Hb + (size_t)node * 512 + lane * 8);
  int head = lane >> 4;
  int dbase = (lane & 15) * 8;
  float sl = 0.f, sr = 0.f;
#pragma unroll
  for (int t = 0; t < 8; t++) {
    float f = (float)v[t];
    sl += f * al[head * 128 + dbase + t];
    sr += f * ar[head * 128 + dbase + t];
  }
#pragma unroll
  for (int off = 1; off < 16; off <<= 1) {
    sl += __shfl_xor(sl, off);
    sr += __shfl_xor(sr, off);
  }
  if ((lane & 15) == 0) {
    el[node * 4 + head] = sl;
    er[node * 4 + head] = sr;
  }
}

// ------------- edge weights (edge-parallel, streaming), per-head PLANES -------
__global__ void edgek(const float* __restrict__ el, const float* __restrict__ er,
                      const int* __restrict__ src, const int* __restrict__ dst,
                      float* __restrict__ pw, int E) {
  int e = blockIdx.x * blockDim.x + threadIdx.x;
  if (e >= E) return;
  int s = src[e], d = dst[e];
  float4 ev = *(const float4*)(el + (size_t)s * 4);
  float4 rv = *(const float4*)(er + (size_t)d * 4);
  float c;
  c = ev.x + rv.x; c = c >= 0.f ? c : 0.2f * c; pw[e] = __expf(c);
  c = ev.y + rv.y; c = c >= 0.f ? c : 0.2f * c; pw[(size_t)E + e] = __expf(c);
  c = ev.z + rv.z; c = c >= 0.f ? c : 0.2f * c; pw[(size_t)2 * E + e] = __expf(c);
  c = ev.w + rv.w; c = c >= 0.f ? c : 0.2f * c; pw[(size_t)3 * E + e] = __expf(c);
}

// ------------- gather-aggregate, DIM-SLICE x XCD partitioned, batch-8 ----------
#define GK_NPB 32  // nodes per block (4 waves x 8 groups); 20000 = 625*32
__global__ __launch_bounds__(256) void gatherk(
    const bf16_t* __restrict__ Hb, const float* __restrict__ pw,
    const int* __restrict__ src, const int* __restrict__ ro,
    const float* __restrict__ bias, bf16_t* __restrict__ out, int N, int E) {
  const int slice = blockIdx.x & 7;
  const int group = blockIdx.x >> 3;
  const int w = threadIdx.x >> 6, lane = threadIdx.x & 63;
  const int g = lane >> 3;               // node sub-index within wave
  const int oct = lane & 7;              // dim octet within slice
  const int head = slice >> 1;
  const float* __restrict__ ph = pw + (size_t)head * E;
  const int dimbase = slice * 64 + oct * 8;

  const int n = group * GK_NPB + w * 8 + g;
  const int e0 = ro[n], e1 = ro[n + 1];

  float acc[8] = {0.f, 0.f, 0.f, 0.f, 0.f, 0.f, 0.f, 0.f};
  float psum = 0.f;

  for (int eb = e0 & ~7; eb < e1; eb += 8) {
    const int4 sv0 = *(const int4*)(src + eb);
    const int4 sv1 = *(const int4*)(src + eb + 4);
    const float4 pv0 = *(const float4*)(ph + eb);
    const float4 pv1 = *(const float4*)(ph + eb + 4);
    int ss[8]; float pp[8];
    ss[0] = sv0.x; ss[1] = sv0.y; ss[2] = sv0.z; ss[3] = sv0.w;
    ss[4] = sv1.x; ss[5] = sv1.y; ss[6] = sv1.z; ss[7] = sv1.w;
    pp[0] = pv0.x; pp[1] = pv0.y; pp[2] = pv0.z; pp[3] = pv0.w;
    pp[4] = pv1.x; pp[5] = pv1.y; pp[6] = pv1.z; pp[7] = pv1.w;
#pragma unroll
    for (int j = 0; j < 8; j++) {
      const int e = eb + j;
      if (e < e0 || e >= e1) pp[j] = 0.f;
    }
    bf16x8 v[8];
#pragma unroll
    for (int j = 0; j < 8; j++)
      v[j] = *(const bf16x8*)(Hb + (size_t)ss[j] * 512 + dimbase);
#pragma unroll
    for (int j = 0; j < 8; j++) {
      psum += pp[j];
#pragma unroll
      for (int t = 0; t < 8; t++) acc[t] += pp[j] * (float)v[j][t];
    }
  }

  const float ih = psum > 0.f ? 1.0f / psum : 0.f;
  const float4 b0 = *(const float4*)(bias + dimbase);
  const float4 b1 = *(const float4*)(bias + dimbase + 4);
  bf16x8 o; float vv;
  vv = acc[0] * ih + b0.x; o[0] = (bf16_t)(vv > 0.f ? vv : expm1f(vv));
  vv = acc[1] * ih + b0.y; o[1] = (bf16_t)(vv > 0.f ? vv : expm1f(vv));
  vv = acc[2] * ih + b0.z; o[2] = (bf16_t)(vv > 0.f ? vv : expm1f(vv));
  vv = acc[3] * ih + b0.w; o[3] = (bf16_t)(vv > 0.f ? vv : expm1f(vv));
  vv = acc[4] * ih + b1.x; o[4] = (bf16_t)(vv > 0.f ? vv : expm1f(vv));
  vv = acc[5] * ih + b1.y; o[5] = (bf16_t)(vv > 0.f ? vv : expm1f(vv));
  vv = acc[6] * ih + b1.z; o[6] = (bf16_t)(vv > 0.f ? vv : expm1f(vv));
  vv = acc[7] * ih + b1.w; o[7] = (bf16_t)(vv > 0.f ? vv : expm1f(vv));
  *(bf16x8*)(out + (size_t)n * 512 + dimbase) = o;
}

// ------------- bf16 MFMA GEMM, 3-STAGE PIPELINED (T3/T4) -------------
// C[M][N] = A[M][K] @ Bt[N][K]^T.  Per iter: wait own tile-k loads
// (counted vmcnt, NEVER 0) -> s_barrier -> issue tile k+2 into the freed
// buffer -> compute tile k.  Tail re-issues the last tile into the dead
// buffer to keep vmcnt uniform.  AF32=1: A fp32 staged via gload_lds with
// XOR-swizzled source segs (r11, correctness-proven), cvt at fragment read.
// EPI=0: bf16 C.  EPI=1: fp32 elu(C+bias).
template <int BM, int BN, int WM, int WN, int EPI, int AF32>
__global__ __launch_bounds__(256) void gemm_bt(
    const void* __restrict__ A, const bf16_t* __restrict__ Bt,
    void* __restrict__ C, const float* __restrict__ bias,
    int M, int N, int K) {
  constexpr int BK = 32;
  constexpr int S = 3;  // pipeline stages
  constexpr int WTM = BM / WM, WTN = BN / WN;
  constexpr int MF = WTM / 16, NF = WTN / 16;
  constexpr int PER = (AF32 ? BM / 32 : BM / 64) + BN / 64;  // issues/wave/stage
  constexpr int WAIT = (S - 2) * PER;
  using AT = typename std::conditional<AF32, float, bf16_t>::type;

  __shared__ AT sA[S][BM][BK];
  __shared__ bf16_t sB[S][BN][BK];

  const bf16_t* __restrict__ Ab = (const bf16_t*)A;
  const float* __restrict__ Af = (const float*)A;

  const int tid = threadIdx.x;
  const int wid = tid >> 6, lane = tid & 63;
  const int wr = wid / WN, wc = wid % WN;

  // XCD-chunked bijective swizzle (m204)
  const int nby = N / BN;
  const int nwg = gridDim.x;
  const int q = nwg >> 3, r = nwg & 7;
  const int xcd = blockIdx.x & 7, pos = blockIdx.x >> 3;
  const int wg = (xcd < r ? xcd * (q + 1) : r * (q + 1) + (xcd - r) * q) + pos;
  const int row0 = (wg / nby) * BM;
  const int col0 = (wg % nby) * BN;

  f32x4 acc[MF][NF];
#pragma unroll
  for (int i = 0; i < MF; i++)
#pragma unroll
    for (int j = 0; j < NF; j++) acc[i][j] = (f32x4){0.f, 0.f, 0.f, 0.f};

  const int lr = lane >> 2;          // bf16 staging: row within 16-row group
  const int lkb = (lane & 3) * 8;    // bf16 staging: k element offset
  const int a_lr = lane >> 3;        // fp32 staging: row within 8-row group
  const int a_seg = (lane & 7) ^ (lane >> 3);  // fp32: XOR-swizzled logical seg

  auto stage = [&](int st, int k0) {
    if constexpr (AF32) {
#pragma unroll
      for (int j = 0; j < BM / 32; j++) {
        const int rj = (j * 4 + wid) * 8;
        int grow = row0 + rj + a_lr; if (grow > M - 1) grow = M - 1;
        gload_lds16(Af + (size_t)grow * K + k0 + a_seg * 4, &sA[st][rj][0]);
      }
    } else {
#pragma unroll
      for (int i = 0; i < BM / 16; i += 4) {
        int r2 = (i + wid) * 16 + lr;
        int grow = row0 + r2; if (grow > M - 1) grow = M - 1;
        gload_lds16(Ab + (size_t)grow * K + k0 + lkb, &sA[st][(i + wid) * 16][0]);
      }
    }
#pragma unroll
    for (int i = 0; i < BN / 16; i += 4) {
      int r2 = (i + wid) * 16 + lr;
      gload_lds16(Bt + (size_t)(col0 + r2) * K + k0 + lkb, &sB[st][(i + wid) * 16][0]);
    }
  };

  const int NT = K / BK;
  // prologue: tiles 0..S-2
#pragma unroll
  for (int t = 0; t < S - 1; t++) stage(t, t * BK);

  for (int k = 0; k < NT; k++) {
    wait_vm<WAIT>();                       // my tile-k loads have landed
    __builtin_amdgcn_sched_barrier(0);
    __builtin_amdgcn_s_barrier();          // everyone's landed; prev reads done
    {
      const int knext = k + S - 1;
      const int tile = knext < NT ? knext : NT - 1;  // tail: dead-buffer reload
      stage(knext % S, tile * BK);
    }
    const int st = k % S;
    bf16x8 af[MF], bfr[NF];
#pragma unroll
    for (int i = 0; i < MF; i++) {
      const int row = wr * WTM + i * 16 + (lane & 15);
      if constexpr (AF32) {
        const int h = lane >> 4;
        const int rowm = row & 7;
        const int p0 = (2 * h) ^ rowm, p1 = (2 * h + 1) ^ rowm;
        const f32x4 a0 = *(const f32x4*)&((const float*)&sA[st][row][0])[p0 * 4];
        const f32x4 a1 = *(const f32x4*)&((const float*)&sA[st][row][0])[p1 * 4];
#pragma unroll
        for (int t = 0; t < 4; t++) {
          af[i][t] = (bf16_t)a0[t];
          af[i][t + 4] = (bf16_t)a1[t];
        }
      } else {
        af[i] = *(const bf16x8*)&((const bf16_t*)&sA[st][row][0])[(lane >> 4) * 8];
      }
    }
#pragma unroll
    for (int j = 0; j < NF; j++)
      bfr[j] = *(const bf16x8*)&sB[st][wc * WTN + j * 16 + (lane & 15)][(lane >> 4) * 8];
#pragma unroll
    for (int i = 0; i < MF; i++)
#pragma unroll
      for (int j = 0; j < NF; j++)
        acc[i][j] = __builtin_amdgcn_mfma_f32_16x16x32_bf16(af[i], bfr[j], acc[i][j], 0, 0, 0);
  }

#pragma unroll
  for (int i = 0; i < MF; i++) {
#pragma unroll
    for (int j = 0; j < NF; j++) {
#pragma unroll
      for (int rr = 0; rr < 4; rr++) {
        int row = row0 + wr * WTM + i * 16 + (lane >> 4) * 4 + rr;
        int col = col0 + wc * WTN + j * 16 + (lane & 15);
        if (row < M) {
          float v = acc[i][j][rr];
          if constexpr (EPI == 0) {
            ((bf16_t*)C)[(size_t)row * N + col] = (bf16_t)v;
          } else {
            v += bias[col];
            v = v > 0.f ? v : expm1f(v);
            ((float*)C)[(size_t)row * N + col] = v;
          }
        }
      }
    }
  }
}

extern "C" void kernel_launch(void* const* d_in, const int* in_sizes, int n_in,
                              void* d_out, int out_size, void* d_ws, size_t ws_size,
                              hipStream_t stream) {
  const float* feature = (const float*)d_in[0];
  const int* src = (const int*)d_in[1];
  const int* dst = (const int*)d_in[2];
  const float* W1 = (const float*)d_in[3];
  const float* al1 = (const float*)d_in[4];
  const float* ar1 = (const float*)d_in[5];
  const float* b1 = (const float*)d_in[6];
  const float* W2 = (const float*)d_in[7];
  const float* al2 = (const float*)d_in[8];
  const float* ar2 = (const float*)d_in[9];
  const float* b2 = (const float*)d_in[10];
  const float* Wfc = (const float*)d_in[11];
  const float* bfc = (const float*)d_in[12];

  const int N = 20000, E = 320000, INF = 1280, HD = 512;

  char* ws = (char*)d_ws;
  size_t off = 0;
  auto alloc = [&](size_t bytes) {
    void* p = ws + off;
    off += (bytes + 255) & ~(size_t)255;
    return p;
  };
  bf16_t* W1t = (bf16_t*)alloc((size_t)HD * INF * 2);
  bf16_t* W2t = (bf16_t*)alloc((size_t)HD * HD * 2);
  bf16_t* Wft = (bf16_t*)alloc((size_t)64 * HD * 2);
  bf16_t* Hb  = (bf16_t*)alloc((size_t)N * HD * 2);    // 20.5 MB
  bf16_t* Xn  = (bf16_t*)alloc((size_t)N * HD * 2);    // 20.5 MB
  float* el = (float*)alloc((size_t)N * 4 * 4);
  float* er = (float*)alloc((size_t)N * 4 * 4);
  float* pw = (float*)alloc((size_t)E * 4 * 4);        // 5.1 MB, planes [4][E]
  int* ro = (int*)alloc((size_t)(N + 1) * 4);

  // preprocessing
  {
    dim3 g(HD / 32, INF / 32);
    transk<<<g, 256, 0, stream>>>(W1, W1t, INF, HD);
  }
  {
    dim3 g(HD / 32, HD / 32);
    transk<<<g, 256, 0, stream>>>(W2, W2t, HD, HD);
  }
  {
    dim3 g(64 / 32, HD / 32);
    transk<<<g, 256, 0, stream>>>(Wfc, Wft, HD, 64);
  }
  rowoffk<<<(N + 1 + 255) / 256, 256, 0, stream>>>(dst, ro, N, E);

  const int nbx = (N + 127) / 128;        // 157
  const int gatherBlocks = (N / GK_NPB) * 8;   // 625 groups x 8 slices
  const int edgeBlocks = (E + 255) / 256;

  // layer 1: A = fp32 feature, pipelined AF32 path (cast fused)
  gemm_bt<128, 128, 2, 2, 0, 1><<<nbx * (HD / 128), 256, 0, stream>>>(
      feature, W1t, Hb, nullptr, N, HD, INF);
  elerk<<<N / 4, 256, 0, stream>>>(Hb, al1, ar1, el, er, N);
  edgek<<<edgeBlocks, 256, 0, stream>>>(el, er, src, dst, pw, E);
  gatherk<<<gatherBlocks, 256, 0, stream>>>(Hb, pw, src, ro, b1, Xn, N, E);

  // layer 2: bf16 path
  gemm_bt<128, 128, 2, 2, 0, 0><<<nbx * (HD / 128), 256, 0, stream>>>(
      Xn, W2t, Hb, nullptr, N, HD, HD);
  elerk<<<N / 4, 256, 0, stream>>>(Hb, al2, ar2, el, er, N);
  edgek<<<edgeBlocks, 256, 0, stream>>>(el, er, src, dst, pw, E);
  gatherk<<<gatherBlocks, 256, 0, stream>>>(Hb, pw, src, ro, b2, Xn, N, E);

  // final FC + elu -> d_out (fp32)
  gemm_bt<128, 64, 4, 1, 1, 0><<<nbx, 256, 0, stream>>>(Xn, Wft, d_out, bfc, N, 64, HD);
}

// Round 13
// 197.697 us; speedup vs baseline: 1.2598x; 1.2598x over previous
//
#include <hip/hip_runtime.h>
#include <hip/hip_bf16.h>
#include <math.h>
#include <type_traits>

typedef __bf16 bf16_t;
typedef __bf16 bf16x8 __attribute__((ext_vector_type(8)));
typedef float f32x4 __attribute__((ext_vector_type(4)));

__device__ __forceinline__ void gload_lds16(const void* g, void* l) {
  __builtin_amdgcn_global_load_lds((const __attribute__((address_space(1))) void*)g,
                                   (__attribute__((address_space(3))) void*)l, 16, 0, 0);
}

// ------------- transpose + cast: in fp32 [K][N] -> out bf16 [N][K] -------------
__global__ void transk(const float* __restrict__ in, bf16_t* __restrict__ out,
                       int K, int N) {
  __shared__ float t[32][33];
  int n0 = blockIdx.x * 32, k0 = blockIdx.y * 32;
  int tx = threadIdx.x & 31, ty = threadIdx.x >> 5;  // ty 0..7
#pragma unroll
  for (int r = ty; r < 32; r += 8) t[r][tx] = in[(size_t)(k0 + r) * N + n0 + tx];
  __syncthreads();
#pragma unroll
  for (int r = ty; r < 32; r += 8)
    out[(size_t)(n0 + r) * K + k0 + tx] = (bf16_t)t[tx][r];
}

// ------------- row offsets: ro[n] = lower_bound(dst, n) (dst sorted) -------------
__global__ void rowoffk(const int* __restrict__ dst, int* __restrict__ ro, int N, int E) {
  int n = blockIdx.x * blockDim.x + threadIdx.x;
  if (n > N) return;
  if (n == N) { ro[N] = E; return; }
  int lo = 0, hi = E;
  while (lo < hi) { int mid = (lo + hi) >> 1; if (dst[mid] < n) lo = mid + 1; else hi = mid; }
  ro[n] = lo;
}

// ------------- el/er: per node, per head dot(h, al), dot(h, ar) -------------
__global__ void elerk(const bf16_t* __restrict__ Hb, const float* __restrict__ al,
                      const float* __restrict__ ar, float* __restrict__ el,
                      float* __restrict__ er, int N) {
  int node = blockIdx.x * 4 + (threadIdx.x >> 6);
  int lane = threadIdx.x & 63;
  if (node >= N) return;
  bf16x8 v = *(const bf16x8*)(Hb + (size_t)node * 512 + lane * 8);
  int head = lane >> 4;
  int dbase = (lane & 15) * 8;
  float sl = 0.f, sr = 0.f;
#pragma unroll
  for (int t = 0; t < 8; t++) {
    float f = (float)v[t];
    sl += f * al[head * 128 + dbase + t];
    sr += f * ar[head * 128 + dbase + t];
  }
#pragma unroll
  for (int off = 1; off < 16; off <<= 1) {
    sl += __shfl_xor(sl, off);
    sr += __shfl_xor(sr, off);
  }
  if ((lane & 15) == 0) {
    el[node * 4 + head] = sl;
    er[node * 4 + head] = sr;
  }
}

// ------------- edge weights (edge-parallel, streaming), per-head PLANES -------
__global__ void edgek(const float* __restrict__ el, const float* __restrict__ er,
                      const int* __restrict__ src, const int* __restrict__ dst,
                      float* __restrict__ pw, int E) {
  int e = blockIdx.x * blockDim.x + threadIdx.x;
  if (e >= E) return;
  int s = src[e], d = dst[e];
  float4 ev = *(const float4*)(el + (size_t)s * 4);
  float4 rv = *(const float4*)(er + (size_t)d * 4);
  float c;
  c = ev.x + rv.x; c = c >= 0.f ? c : 0.2f * c; pw[e] = __expf(c);
  c = ev.y + rv.y; c = c >= 0.f ? c : 0.2f * c; pw[(size_t)E + e] = __expf(c);
  c = ev.z + rv.z; c = c >= 0.f ? c : 0.2f * c; pw[(size_t)2 * E + e] = __expf(c);
  c = ev.w + rv.w; c = c >= 0.f ? c : 0.2f * c; pw[(size_t)3 * E + e] = __expf(c);
}

// ------------- gather-aggregate, DIM-SLICE x XCD partitioned, batch-8 ----------
#define GK_NPB 32  // nodes per block (4 waves x 8 groups); 20000 = 625*32
__global__ __launch_bounds__(256) void gatherk(
    const bf16_t* __restrict__ Hb, const float* __restrict__ pw,
    const int* __restrict__ src, const int* __restrict__ ro,
    const float* __restrict__ bias, bf16_t* __restrict__ out, int N, int E) {
  const int slice = blockIdx.x & 7;
  const int group = blockIdx.x >> 3;
  const int w = threadIdx.x >> 6, lane = threadIdx.x & 63;
  const int g = lane >> 3;               // node sub-index within wave
  const int oct = lane & 7;              // dim octet within slice
  const int head = slice >> 1;
  const float* __restrict__ ph = pw + (size_t)head * E;
  const int dimbase = slice * 64 + oct * 8;

  const int n = group * GK_NPB + w * 8 + g;
  const int e0 = ro[n], e1 = ro[n + 1];

  float acc[8] = {0.f, 0.f, 0.f, 0.f, 0.f, 0.f, 0.f, 0.f};
  float psum = 0.f;

  for (int eb = e0 & ~7; eb < e1; eb += 8) {
    const int4 sv0 = *(const int4*)(src + eb);
    const int4 sv1 = *(const int4*)(src + eb + 4);
    const float4 pv0 = *(const float4*)(ph + eb);
    const float4 pv1 = *(const float4*)(ph + eb + 4);
    int ss[8]; float pp[8];
    ss[0] = sv0.x; ss[1] = sv0.y; ss[2] = sv0.z; ss[3] = sv0.w;
    ss[4] = sv1.x; ss[5] = sv1.y; ss[6] = sv1.z; ss[7] = sv1.w;
    pp[0] = pv0.x; pp[1] = pv0.y; pp[2] = pv0.z; pp[3] = pv0.w;
    pp[4] = pv1.x; pp[5] = pv1.y; pp[6] = pv1.z; pp[7] = pv1.w;
#pragma unroll
    for (int j = 0; j < 8; j++) {
      const int e = eb + j;
      if (e < e0 || e >= e1) pp[j] = 0.f;
    }
    bf16x8 v[8];
#pragma unroll
    for (int j = 0; j < 8; j++)
      v[j] = *(const bf16x8*)(Hb + (size_t)ss[j] * 512 + dimbase);
#pragma unroll
    for (int j = 0; j < 8; j++) {
      psum += pp[j];
#pragma unroll
      for (int t = 0; t < 8; t++) acc[t] += pp[j] * (float)v[j][t];
    }
  }

  const float ih = psum > 0.f ? 1.0f / psum : 0.f;
  const float4 b0 = *(const float4*)(bias + dimbase);
  const float4 b1 = *(const float4*)(bias + dimbase + 4);
  bf16x8 o; float vv;
  vv = acc[0] * ih + b0.x; o[0] = (bf16_t)(vv > 0.f ? vv : expm1f(vv));
  vv = acc[1] * ih + b0.y; o[1] = (bf16_t)(vv > 0.f ? vv : expm1f(vv));
  vv = acc[2] * ih + b0.z; o[2] = (bf16_t)(vv > 0.f ? vv : expm1f(vv));
  vv = acc[3] * ih + b0.w; o[3] = (bf16_t)(vv > 0.f ? vv : expm1f(vv));
  vv = acc[4] * ih + b1.x; o[4] = (bf16_t)(vv > 0.f ? vv : expm1f(vv));
  vv = acc[5] * ih + b1.y; o[5] = (bf16_t)(vv > 0.f ? vv : expm1f(vv));
  vv = acc[6] * ih + b1.z; o[6] = (bf16_t)(vv > 0.f ? vv : expm1f(vv));
  vv = acc[7] * ih + b1.w; o[7] = (bf16_t)(vv > 0.f ? vv : expm1f(vv));
  *(bf16x8*)(out + (size_t)n * 512 + dimbase) = o;
}

// ------------- bf16 MFMA GEMM, BK=64, single-buffered 2-barrier -------------
// r12 lesson: counted-vmcnt pipeline regressed (T3/T4 needs the full 8-phase
// structure). Attack the per-step overhead instead: BK 32->64 halves the
// barrier count at constant per-step cost. 128 B LDS rows would be 16-way
// bank-conflicted, so all tiles use the seg-XOR swizzle proven in r11's AF32
// path (rule #21): linear gload_lds DEST + inverse-swizzled SOURCE k-offset +
// swizzled read: phys_seg = logical_seg ^ (row&7) -> ~2 lanes/bank (free).
// AF32=1: A fp32 (GEMM1, fuses the fp32->bf16 cast; cvt at fragment read).
// EPI=0: bf16 C.  EPI=1: fp32 elu(C+bias).
template <int BM, int BN, int WM, int WN, int EPI, int AF32>
__global__ __launch_bounds__(256) void gemm_bt(
    const void* __restrict__ A, const bf16_t* __restrict__ Bt,
    void* __restrict__ C, const float* __restrict__ bias,
    int M, int N, int K) {
  constexpr int BK = 64;
  constexpr int WTM = BM / WM, WTN = BN / WN;
  constexpr int MF = WTM / 16, NF = WTN / 16;
  using AT = typename std::conditional<AF32, float, bf16_t>::type;

  __shared__ AT sA[BM][BK];
  __shared__ bf16_t sB[BN][BK];

  const bf16_t* __restrict__ Ab = (const bf16_t*)A;
  const float* __restrict__ Af = (const float*)A;

  const int tid = threadIdx.x;
  const int wid = tid >> 6, lane = tid & 63;
  const int wr = wid / WN, wc = wid % WN;

  // XCD-chunked bijective swizzle (m204)
  const int nby = N / BN;
  const int nwg = gridDim.x;
  const int q = nwg >> 3, r = nwg & 7;
  const int xcd = blockIdx.x & 7, pos = blockIdx.x >> 3;
  const int wg = (xcd < r ? xcd * (q + 1) : r * (q + 1) + (xcd - r) * q) + pos;
  const int row0 = (wg / nby) * BM;
  const int col0 = (wg % nby) * BN;

  f32x4 acc[MF][NF];
#pragma unroll
  for (int i = 0; i < MF; i++)
#pragma unroll
    for (int j = 0; j < NF; j++) acc[i][j] = (f32x4){0.f, 0.f, 0.f, 0.f};

  // bf16 staging: 1 KB/issue = 8 rows of 128 B; lane -> row l>>3, phys seg l&7
  const int b_r = lane >> 3, b_p = lane & 7;
  // fp32 staging: 1 KB/issue = 4 rows of 256 B; lane -> row l>>4, phys seg l&15
  const int a_r = lane >> 4, a_p = lane & 15;

  for (int k0 = 0; k0 < K; k0 += BK) {
    if constexpr (AF32) {
#pragma unroll
      for (int j = 0; j < BM / 16; j++) {      // 32 issues, 8/wave, 4 rows each
        const int rj = (j * 4 + wid) * 4;
        const int row = rj + a_r;
        int grow = row0 + row; if (grow > M - 1) grow = M - 1;
        const int s = a_p ^ (row & 7);         // inverse swizzle on source
        gload_lds16(Af + (size_t)grow * K + k0 + s * 4, &sA[rj][0]);
      }
    } else {
#pragma unroll
      for (int j = 0; j < BM / 32; j++) {      // 16 issues, 4/wave, 8 rows each
        const int rj = (j * 4 + wid) * 8;
        const int row = rj + b_r;
        int grow = row0 + row; if (grow > M - 1) grow = M - 1;
        const int s = b_p ^ (row & 7);
        gload_lds16(Ab + (size_t)grow * K + k0 + s * 8, &sA[rj][0]);
      }
    }
#pragma unroll
    for (int j = 0; j < BN / 32; j++) {
      const int rj = (j * 4 + wid) * 8;
      const int row = rj + b_r;
      const int s = b_p ^ (row & 7);
      gload_lds16(Bt + (size_t)(col0 + row) * K + k0 + s * 8, &sB[rj][0]);
    }
    __syncthreads();

#pragma unroll
    for (int kk = 0; kk < BK; kk += 32) {
      bf16x8 af[MF], bfr[NF];
#pragma unroll
      for (int i = 0; i < MF; i++) {
        const int row = wr * WTM + i * 16 + (lane & 15);
        if constexpr (AF32) {
          const int s0 = kk / 4 + (lane >> 4) * 2;      // 16B segs of 4 floats
          const int p0 = s0 ^ (row & 7), p1 = (s0 + 1) ^ (row & 7);
          const f32x4 a0 = *(const f32x4*)&((const float*)&sA[row][0])[p0 * 4];
          const f32x4 a1 = *(const f32x4*)&((const float*)&sA[row][0])[p1 * 4];
#pragma unroll
          for (int t = 0; t < 4; t++) {
            af[i][t] = (bf16_t)a0[t];
            af[i][t + 4] = (bf16_t)a1[t];
          }
        } else {
          const int s = kk / 8 + (lane >> 4);           // 16B segs of 8 bf16
          const int p = s ^ (row & 7);
          af[i] = *(const bf16x8*)&((const bf16_t*)&sA[row][0])[p * 8];
        }
      }
#pragma unroll
      for (int j = 0; j < NF; j++) {
        const int row = wc * WTN + j * 16 + (lane & 15);
        const int s = kk / 8 + (lane >> 4);
        const int p = s ^ (row & 7);
        bfr[j] = *(const bf16x8*)&((const bf16_t*)&sB[row][0])[p * 8];
      }
#pragma unroll
      for (int i = 0; i < MF; i++)
#pragma unroll
        for (int j = 0; j < NF; j++)
          acc[i][j] = __builtin_amdgcn_mfma_f32_16x16x32_bf16(af[i], bfr[j], acc[i][j], 0, 0, 0);
    }
    __syncthreads();
  }

#pragma unroll
  for (int i = 0; i < MF; i++) {
#pragma unroll
    for (int j = 0; j < NF; j++) {
#pragma unroll
      for (int rr = 0; rr < 4; rr++) {
        int row = row0 + wr * WTM + i * 16 + (lane >> 4) * 4 + rr;
        int col = col0 + wc * WTN + j * 16 + (lane & 15);
        if (row < M) {
          float v = acc[i][j][rr];
          if constexpr (EPI == 0) {
            ((bf16_t*)C)[(size_t)row * N + col] = (bf16_t)v;
          } else {
            v += bias[col];
            v = v > 0.f ? v : expm1f(v);
            ((float*)C)[(size_t)row * N + col] = v;
          }
        }
      }
    }
  }
}

extern "C" void kernel_launch(void* const* d_in, const int* in_sizes, int n_in,
                              void* d_out, int out_size, void* d_ws, size_t ws_size,
                              hipStream_t stream) {
  const float* feature = (const float*)d_in[0];
  const int* src = (const int*)d_in[1];
  const int* dst = (const int*)d_in[2];
  const float* W1 = (const float*)d_in[3];
  const float* al1 = (const float*)d_in[4];
  const float* ar1 = (const float*)d_in[5];
  const float* b1 = (const float*)d_in[6];
  const float* W2 = (const float*)d_in[7];
  const float* al2 = (const float*)d_in[8];
  const float* ar2 = (const float*)d_in[9];
  const float* b2 = (const float*)d_in[10];
  const float* Wfc = (const float*)d_in[11];
  const float* bfc = (const float*)d_in[12];

  const int N = 20000, E = 320000, INF = 1280, HD = 512;

  char* ws = (char*)d_ws;
  size_t off = 0;
  auto alloc = [&](size_t bytes) {
    void* p = ws + off;
    off += (bytes + 255) & ~(size_t)255;
    return p;
  };
  bf16_t* W1t = (bf16_t*)alloc((size_t)HD * INF * 2);
  bf16_t* W2t = (bf16_t*)alloc((size_t)HD * HD * 2);
  bf16_t* Wft = (bf16_t*)alloc((size_t)64 * HD * 2);
  bf16_t* Hb  = (bf16_t*)alloc((size_t)N * HD * 2);    // 20.5 MB
  bf16_t* Xn  = (bf16_t*)alloc((size_t)N * HD * 2);    // 20.5 MB
  float* el = (float*)alloc((size_t)N * 4 * 4);
  float* er = (float*)alloc((size_t)N * 4 * 4);
  float* pw = (float*)alloc((size_t)E * 4 * 4);        // 5.1 MB, planes [4][E]
  int* ro = (int*)alloc((size_t)(N + 1) * 4);

  // preprocessing
  {
    dim3 g(HD / 32, INF / 32);
    transk<<<g, 256, 0, stream>>>(W1, W1t, INF, HD);
  }
  {
    dim3 g(HD / 32, HD / 32);
    transk<<<g, 256, 0, stream>>>(W2, W2t, HD, HD);
  }
  {
    dim3 g(64 / 32, HD / 32);
    transk<<<g, 256, 0, stream>>>(Wfc, Wft, HD, 64);
  }
  rowoffk<<<(N + 1 + 255) / 256, 256, 0, stream>>>(dst, ro, N, E);

  const int nbx = (N + 127) / 128;        // 157
  const int gatherBlocks = (N / GK_NPB) * 8;   // 625 groups x 8 slices
  const int edgeBlocks = (E + 255) / 256;

  // layer 1: A = fp32 feature (cast fused into staging), BK=64
  gemm_bt<128, 128, 2, 2, 0, 1><<<nbx * (HD / 128), 256, 0, stream>>>(
      feature, W1t, Hb, nullptr, N, HD, INF);
  elerk<<<N / 4, 256, 0, stream>>>(Hb, al1, ar1, el, er, N);
  edgek<<<edgeBlocks, 256, 0, stream>>>(el, er, src, dst, pw, E);
  gatherk<<<gatherBlocks, 256, 0, stream>>>(Hb, pw, src, ro, b1, Xn, N, E);

  // layer 2: bf16 path, BK=64
  gemm_bt<128, 128, 2, 2, 0, 0><<<nbx * (HD / 128), 256, 0, stream>>>(
      Xn, W2t, Hb, nullptr, N, HD, HD);
  elerk<<<N / 4, 256, 0, stream>>>(Hb, al2, ar2, el, er, N);
  edgek<<<edgeBlocks, 256, 0, stream>>>(el, er, src, dst, pw, E);
  gatherk<<<gatherBlocks, 256, 0, stream>>>(Hb, pw, src, ro, b2, Xn, N, E);

  // final FC + elu -> d_out (fp32)
  gemm_bt<128, 64, 4, 1, 1, 0><<<nbx, 256, 0, stream>>>(Xn, Wft, d_out, bfc, N, 64, HD);
}